// Round 9
// baseline (43.444 us; speedup 1.0000x reference)
//
#include <hip/hip_runtime.h>
#include <math.h>

#define NB 768
#define ND 128
#define NC 12            // NB / 64 lane-chunks (mining layout)
#define APB 3            // anchors per block in K1 -> 256 blocks
#define TL_MARGIN 1.0f
#define TL_EPS 1e-12f
#define SCALE 16777216.0f   // 2^24 fixed-point for deterministic atomic sum

// ws layout (bytes):
//   ET     @ 0x00000 : 128*768 f32 = 384 KB   (ET[k][j] = E[j][k])
//   sq     @ 0x60000 : 768 f32
//   psumI  @ 0x61000 : unsigned long long
//   pcntI  @ 0x61008 : int
//   ticket @ 0x6100C : int

// ---- K0: transpose + sq (384 blocks x 256 thr) + zero accumulators ----
__global__ __launch_bounds__(256) void transpose_sq_kernel(
    const float* __restrict__ E, float* __restrict__ ET, float* __restrict__ sq,
    unsigned long long* __restrict__ psumI, int* __restrict__ pcntI,
    int* __restrict__ ticket)
{
    __shared__ float part[4];
    const int b    = blockIdx.x;
    const int tid  = threadIdx.x;
    const int lane = tid & 63;
    const int wave = tid >> 6;

    if (b == 0 && tid == 0) { *psumI = 0ull; *pcntI = 0; *ticket = 0; }

    const int idx = b * 256 + tid;        // global element index, coalesced
    const float v = E[idx];
    const int j = idx >> 7;               // row
    const int k = idx & 127;              // col
    ET[(size_t)k * NB + j] = v;           // scattered store, fire-and-forget

    // wave w holds 64 consecutive k of row (2b + w/2); reduce v^2
    float s = v * v;
    #pragma unroll
    for (int off = 32; off > 0; off >>= 1) s += __shfl_xor(s, off);
    if (lane == 0) part[wave] = s;
    __syncthreads();
    if (tid == 0) {
        sq[2 * b]     = part[0] + part[1];
        sq[2 * b + 1] = part[2] + part[3];
    }
}

// ---- K1: fused distance + mining + grid reduction; 256 blocks x 768 thr ----
__global__ __launch_bounds__(768) void triplet_fused_kernel(
    const float* __restrict__ E, const float* __restrict__ ET,
    const float* __restrict__ sq, const int* __restrict__ L,
    unsigned long long* __restrict__ psumI, int* __restrict__ pcntI,
    int* __restrict__ ticket, float* __restrict__ out)
{
    __shared__ float drow[APB][NB];        // 9 KB

    const int tid  = threadIdx.x;
    const int lane = tid & 63;
    const int wave = tid >> 6;             // 0..11
    int i0 = blockIdx.x * APB;
    i0 = __builtin_amdgcn_readfirstlane(i0);

    // anchor rows via wave-uniform pointers -> scalar (SGPR) loads
    const float* __restrict__ A0 = E + (size_t)(i0 + 0) * ND;
    const float* __restrict__ A1 = E + (size_t)(i0 + 1) * ND;
    const float* __restrict__ A2 = E + (size_t)(i0 + 2) * ND;
    const float sqa0 = sq[i0], sqa1 = sq[i0 + 1], sqa2 = sq[i0 + 2];

    // ---- distance: wave w covers j in [w*64, w*64+64), one dword per lane ----
    {
        const float* __restrict__ Bcol = ET + (wave * 64 + lane);
        float p0 = 0.f, p1 = 0.f, p2 = 0.f;
        #pragma unroll 8
        for (int k = 0; k < ND; ++k) {
            float b = Bcol[(size_t)k * NB];     // coalesced 256 B per wave-instr
            float a0 = A0[k], a1 = A1[k], a2 = A2[k];   // SGPR broadcasts
            p0 += a0 * b; p1 += a1 * b; p2 += a2 * b;
        }
        const int j = wave * 64 + lane;
        const float sjv = sq[j];
        drow[0][j] = sqrtf(fmaxf(sqa0 + sjv - 2.f * p0, TL_EPS));
        drow[1][j] = sqrtf(fmaxf(sqa1 + sjv - 2.f * p1, TL_EPS));
        drow[2][j] = sqrtf(fmaxf(sqa2 + sjv - 2.f * p2, TL_EPS));
    }
    __syncthreads();

    // ---- mining: waves 0..2, wave = anchor (proven code) ----
    if (wave < APB) {
        const int ia = i0 + wave;
        const int li = L[ia];
        unsigned negm = 0u, posm = 0u;
        float dk[NC];
        #pragma unroll
        for (int c = 0; c < NC; ++c) {
            int j = c * 64 + lane;
            dk[c] = drow[wave][j];
            int lj = L[j];
            if (lj != li)     negm |= (1u << c);
            else if (j != ia) posm |= (1u << c);
        }

        float bv = INFINITY;
        #pragma unroll
        for (int c = 0; c < NC; ++c)
            if ((negm >> c) & 1u) bv = fminf(bv, dk[c]);
        #pragma unroll
        for (int off = 32; off > 0; off >>= 1)
            bv = fminf(bv, __shfl_xor(bv, off));
        const float hval = bv;

        float lsum = 0.f, lcnt = 0.f;
        if (isfinite(hval)) {
            #pragma unroll
            for (int c = 0; c < NC; ++c) {
                unsigned long long pm = __ballot((posm >> c) & 1u);
                while (pm) {
                    const int sl = __builtin_ctzll(pm);
                    pm &= pm - 1;
                    const float pd = __shfl(dk[c], sl);
                    float nd = hval;
                    #pragma unroll
                    for (int c2 = 0; c2 < NC; ++c2) {
                        bool pred = ((negm >> c2) & 1u) &&
                                    (dk[c2] > pd) && (dk[c2] < pd + TL_MARGIN);
                        unsigned long long m = __ballot(pred);
                        if (m) { nd = __shfl(dk[c2], __builtin_ctzll(m)); break; }
                    }
                    lsum += fmaxf(pd - nd + TL_MARGIN, 0.f);
                    lcnt += 1.f;
                }
            }
        }
        if (lane == 0) {
            atomicAdd(psumI, (unsigned long long)llrintf(lsum * SCALE));
            atomicAdd(pcntI, (int)(lcnt + 0.5f));
        }
    }
    __syncthreads();   // drains this block's atomics (waitcnt before barrier)

    // ---- last block finalizes (exact integer sums -> deterministic) ----
    if (tid == 0) {
        __threadfence();
        int t = atomicAdd(ticket, 1);
        if (t == (int)gridDim.x - 1) {
            unsigned long long s = atomicAdd(psumI, 0ull);  // coherent read
            int c = atomicAdd(pcntI, 0);
            double sum = (double)s * (1.0 / (double)SCALE);
            int cd = c > 1 ? c : 1;
            out[0] = (float)(sum / (double)cd);
        }
    }
}

extern "C" void kernel_launch(void* const* d_in, const int* in_sizes, int n_in,
                              void* d_out, int out_size, void* d_ws, size_t ws_size,
                              hipStream_t stream) {
    const float* E = (const float*)d_in[0];
    const int*   L = (const int*)d_in[1];
    char* ws = (char*)d_ws;
    float* ET   = (float*)(ws);
    float* sq   = (float*)(ws + 0x60000);
    unsigned long long* psumI = (unsigned long long*)(ws + 0x61000);
    int* pcntI  = (int*)(ws + 0x61008);
    int* ticket = (int*)(ws + 0x6100C);
    float* out  = (float*)d_out;

    transpose_sq_kernel<<<NB * ND / 256, 256, 0, stream>>>(E, ET, sq, psumI, pcntI, ticket);
    triplet_fused_kernel<<<NB / APB, 768, 0, stream>>>(E, ET, sq, L, psumI, pcntI, ticket, out);
}